// Round 11
// baseline (301.936 us; speedup 1.0000x reference)
//
#include <hip/hip_runtime.h>
#include <stdint.h>

// x: (32, 256, 58, 58) f32 binary {0,1};  w: (256, 256, 3, 3) f32
// out: (32, 256, 56, 56) f32 = alpha[o]*(2S - 2304)
// R14: i8 MFMA implicit conv.
// R10 post-mortem: MfmaUtil 34.3% x 86.2us = 29.6us = the MFMA floor; the
// pipe is idle 2/3 of the time. Occupancy 33% (~2.67 waves/SIMD, unified
// file ~192/wave with accs AGPR-homed but asm demanding "v" copies-free
// arch residency). Fix: accs pinned "+a" (AGPR-native MFMA operands),
// waves_per_eu(4) (arch ~55 + agpr 64 <= 128 -> 4 waves/SIMD), and A-frag
// ds_reads software-pipelined one K-step ahead. Also pack_x rewritten
// read-coalesced (it reads 110MB; old mapping got 64B segments).

#define BATCH 32
#define C_IN 256
#define OCH 256
#define HIN 58
#define WIN2 58
#define HOUT 56
#define WOUT 56
#define TAPS 9
#define WWORDS 8            // 256 channels / 32 bits
#define HWIN (HIN * WIN2)   // 3364
#define HWOUT (HOUT * WOUT) // 3136
#define NPOS (BATCH * HWIN) // 107648

#define AP 144              // LDS bytes per input position (128 ch + 16 pad:
                            // 16B-slot stride 9 (odd) -> b128 slots rotate, ~conflict-free)
#define NAPOS 232           // 4 input rows * 58

typedef int   i32x4  __attribute__((ext_vector_type(4)));
typedef int   i32x16 __attribute__((ext_vector_type(16)));
typedef float f32x4  __attribute__((ext_vector_type(4)));

// MFMA via inline asm (verified R9/R10, absmax 0.0). Accumulator class is
// AGPR ("a"): MFMA reads/writes AGPRs natively -> no per-use copies AND the
// arch-VGPR file stays free for the load pipeline.
#define MFMA(acc, va, vb) \
    asm volatile("v_mfma_i32_32x32x32_i8 %0, %1, %2, %0" : "+a"(acc) : "v"(va), "v"(vb))

// ---------------------------------------------------------------------------
// Kernel 1: bit-pack x. R14: thread <-> ONE position, all 8 words.
// Reads: for each channel j, 64 lanes read 64 consecutive floats -> 256B
// fully-coalesced segments (110 MB total; the old mapping got 64B segs).
// Writes: 32B/lane contiguous (uint4 x2) -> 2KB/wave.
// ---------------------------------------------------------------------------
__global__ __launch_bounds__(256) void pack_x_kernel(
    const float* __restrict__ x, uint32_t* __restrict__ xp)
{
    int p = blockIdx.x * 256 + threadIdx.x;      // 421 blocks, tail-guarded
    if (p >= NPOS) return;
    int b = p / HWIN;
    int r = p - b * HWIN;
    const float* xb = x + (size_t)b * C_IN * HWIN + r;
    uint32_t w[8];
    #pragma unroll
    for (int k = 0; k < 8; ++k) {
        uint32_t m = 0u;
        #pragma unroll
        for (int j = 0; j < 32; ++j)
            m |= (xb[(size_t)(k * 32 + j) * HWIN] > 0.5f ? 1u : 0u) << j;
        w[k] = m;
    }
    *(uint4*)(xp + (size_t)p * WWORDS)     = make_uint4(w[0], w[1], w[2], w[3]);
    *(uint4*)(xp + (size_t)p * WWORDS + 4) = make_uint4(w[4], w[5], w[6], w[7]);
}

// ---------------------------------------------------------------------------
// Kernel 2: pack weights to i8 {+1,-1}, STEP-MAJOR (unchanged, verified):
//   wq8s[((s*2 + e)*256 + o)*16 + j], s = kh*36 + tap*4 + kb,
//   weight channel c = kh*128 + kb*32 + e*16 + j. Also alpha per o.
// ---------------------------------------------------------------------------
__global__ __launch_bounds__(256) void pack_w8_kernel(
    const float* __restrict__ wt, char* __restrict__ wq8s, float* __restrict__ sA)
{
    int o = blockIdx.x;
    int c = threadIdx.x;
    const float* wb = wt + ((size_t)o * C_IN + c) * TAPS;
    float s = 0.f;
    char sg[TAPS];
    #pragma unroll
    for (int t = 0; t < TAPS; ++t) {
        float v = wb[t];
        s += fabsf(v);
        sg[t] = (v >= 0.0f) ? (char)1 : (char)-1;
    }
    int kh = c >> 7;
    int kb = (c >> 5) & 3;
    int e  = (c >> 4) & 1;
    int j  = c & 15;
    #pragma unroll
    for (int t = 0; t < TAPS; ++t) {
        int st = kh * 36 + t * 4 + kb;
        wq8s[(size_t)((st * 2 + e) * 256 + o) * 16 + j] = sg[t];
    }

    __shared__ float red[256];
    red[c] = s;
    __syncthreads();
    for (int off = 128; off > 0; off >>= 1) {
        if (c < off) red[c] += red[c + off];
        __syncthreads();
    }
    if (c == 0) sA[o] = red[0] / (float)(C_IN * HWIN);
}

// ---------------------------------------------------------------------------
// Kernel 3: main i8-MFMA conv. Block = 2 output rows (M=128: 112 valid) x
// N=256 o. 8 waves, wave = 2M x 2N quad of 32x32x32 tiles.
// A: bit->+-1 expand into LDS per K-half (stride AP=144), restaged once.
//    Frag ds_reads pipelined one step ahead (a_cur/a_next), reloaded across
//    the restage boundary (s=35/71 skip, s=36 reload after barrier).
// B: registers straight from global (L2-resident), 3-deep prefetch.
// Accs: 64 AGPRs via "+a". Arch VGPRs ~55 -> 4 waves/SIMD with
// waves_per_eu(4).
// ---------------------------------------------------------------------------
__global__ __launch_bounds__(512)
__attribute__((amdgpu_waves_per_eu(4)))
void xnor_mfma_kernel(
    const uint32_t* __restrict__ xp, const char* __restrict__ wq8s,
    const float* __restrict__ sA, float* __restrict__ out)
{
    __shared__ __attribute__((aligned(16))) char lds[36864]; // A 33,408 / Cbuf 36,864
    char* Alds = lds;
    float* Cbuf = (float*)lds;                   // epilogue alias

    int blk = blockIdx.x;                        // 0..895
    int b   = blk / 28;                          // 28 row-pairs per image
    int rp  = blk - b * 28;
    int oy0 = rp * 2;
    int tid  = threadIdx.x;
    int wv   = tid >> 6;
    int lane = tid & 63;
    int l31  = lane & 31;
    int e    = lane >> 5;
    int mgrp = wv & 1;                           // M-half of this wave
    int ngrp = wv >> 1;                          // o-group (64 o)

    // Per-lane A-frag base for the wave's 2 M-subtiles (row = l31).
    int baseA[2];
    #pragma unroll
    for (int mi = 0; mi < 2; ++mi) {
        int p = (mgrp * 2 + mi) * 32 + l31;      // 0..127
        int r = (p * 586) >> 15;                 // p/56 exact for p<=127
        int c = p - 56 * r;
        baseA[mi] = (r * 58 + c) * AP + e * 16;
    }
    // B-fragment per-lane base in step-major wq8s; step stride = 8192 B.
    const char* pb = wq8s + ((size_t)e * 256 + (size_t)(ngrp * 64 + l31)) * 16;
    float al0 = sA[ngrp * 64 + l31];
    float al1 = sA[ngrp * 64 + 32 + l31];

    i32x16 acc00 = {0}, acc01 = {0}, acc10 = {0}, acc11 = {0};
    asm volatile("" : "+a"(acc00), "+a"(acc01), "+a"(acc10), "+a"(acc11)); // pin init above
    asm volatile("s_nop 7\n\ts_nop 7");          // VALU->MFMA srcC hazard guard

// A K-step LDS offset (compile-time under full unroll); kh enters only via
// which half is currently staged.
#define KA(s) ((((((s) % 36) >> 2) / 3) * 58 + ((((s) % 36) >> 2) % 3)) * AP + ((s) & 3) * 32)

// Expand bit-packed x into +-1 bytes for K-half KH (verified R9/R10).
#define STAGE_A(KH)                                                        \
    {                                                                      \
        _Pragma("unroll")                                                  \
        for (int ir = 0; ir < 4; ++ir) {                                   \
            if (tid < 464) {                                               \
                int iw = tid >> 3, c16 = tid & 7;                          \
                uint32_t wvx = xp[((size_t)(b * HIN + oy0 + ir) * WIN2 + iw) * WWORDS \
                                  + (KH) * 4 + (c16 >> 1)];                \
                uint32_t bits = (c16 & 1) ? (wvx >> 16) : (wvx & 0xFFFFu); \
                i32x4 v;                                                   \
                _Pragma("unroll")                                          \
                for (int d = 0; d < 4; ++d) {                              \
                    uint32_t n  = (bits >> (4 * d)) & 0xFu;                \
                    uint32_t sp = (n * 0x204081u) & 0x01010101u;           \
                    v[d] = (int)~(sp * 0xFEu);                             \
                }                                                          \
                *(i32x4*)(Alds + (ir * 58 + iw) * AP + c16 * 16) = v;      \
            }                                                              \
        }                                                                  \
    }

    STAGE_A(0);

    // B prefetch prologue: steps 0,1,2 in registers.
    i32x4 rb0[3], rb1[3];
    #pragma unroll
    for (int q = 0; q < 3; ++q) {
        rb0[q] = *(const i32x4*)(pb + (size_t)q * 8192);
        rb1[q] = *(const i32x4*)(pb + (size_t)q * 8192 + 512);
    }
    __syncthreads();

    // A pipeline prologue: step 0 fragments.
    i32x4 a0c = *(const i32x4*)(Alds + baseA[0] + KA(0));
    i32x4 a1c = *(const i32x4*)(Alds + baseA[1] + KA(0));

    #pragma unroll
    for (int s = 0; s < 72; ++s) {               // s = kh*36 + tap*4 + kb
        if (s == 36) {                           // half-K A restage
            __syncthreads();
            STAGE_A(1);
            __syncthreads();
            a0c = *(const i32x4*)(Alds + baseA[0] + KA(36));
            a1c = *(const i32x4*)(Alds + baseA[1] + KA(36));
        }
        // B prefetch for s+3 (tail reload harmless).
        const int s3 = (s + 3 > 71) ? 71 : s + 3;
        i32x4 nb0 = *(const i32x4*)(pb + (size_t)s3 * 8192);
        i32x4 nb1 = *(const i32x4*)(pb + (size_t)s3 * 8192 + 512);
        // A prefetch for s+1 (same half; boundary steps reload current).
        const int sn = (s == 35 || s == 71) ? s : s + 1;
        i32x4 na0 = *(const i32x4*)(Alds + baseA[0] + KA(sn));
        i32x4 na1 = *(const i32x4*)(Alds + baseA[1] + KA(sn));

        i32x4 b0 = rb0[s % 3];
        i32x4 b1 = rb1[s % 3];
        MFMA(acc00, a0c, b0);
        MFMA(acc01, a0c, b1);
        MFMA(acc10, a1c, b0);
        MFMA(acc11, a1c, b1);

        rb0[s % 3] = nb0; rb1[s % 3] = nb1;
        a0c = na0; a1c = na1;
    }

    asm volatile("s_nop 7\n\ts_nop 7");          // MFMA->VALU read guard

    // Epilogue (verified R9/R10): D layout col = l31,
    // row = (reg&3) + 8*(reg>>2) + 4*e. 4 quarter-M phases via Cbuf[o][36].
    size_t ob = ((size_t)b * OCH) * HWOUT + (size_t)oy0 * WOUT;
    #pragma unroll
    for (int q = 0; q < 4; ++q) {
        __syncthreads();
        if (mgrp == (q >> 1)) {
            const int mi = q & 1;
            #pragma unroll
            for (int ni = 0; ni < 2; ++ni) {
                float al = ni ? al1 : al0;
                int o = ngrp * 64 + ni * 32 + l31;
                i32x16 A;
                if (mi == 0 && ni == 0) A = acc00;
                else if (mi == 0)       A = acc01;
                else if (ni == 0)       A = acc10;
                else                    A = acc11;
                #pragma unroll
                for (int g = 0; g < 4; ++g) {
                    f32x4 vv;
                    vv[0] = al * (float)A[4 * g + 0];
                    vv[1] = al * (float)A[4 * g + 1];
                    vv[2] = al * (float)A[4 * g + 2];
                    vv[3] = al * (float)A[4 * g + 3];
                    int pl = g * 8 + 4 * e;                // pos within quarter
                    *(f32x4*)(Cbuf + (size_t)o * 36 + pl) = vv;
                }
            }
        }
        __syncthreads();
        #pragma unroll 1
        for (int i = 0; i < 16; ++i) {           // flush 256 o x 32 pos
            int idx = i * 512 + tid;
            int o = idx >> 5, pl = idx & 31;
            int pg = q * 32 + pl;
            if (pg < 112) {
                int r = (pg >= 56) ? 1 : 0;
                int c = pg - 56 * r;
                out[ob + (size_t)o * HWOUT + r * WOUT + c] = Cbuf[o * 36 + pl];
            }
        }
    }
#undef STAGE_A
#undef KA
}

// ---------------------------------------------------------------------------
extern "C" void kernel_launch(void* const* d_in, const int* in_sizes, int n_in,
                              void* d_out, int out_size, void* d_ws, size_t ws_size,
                              hipStream_t stream)
{
    const float* x  = (const float*)d_in[0];
    const float* wt = (const float*)d_in[1];
    float* out = (float*)d_out;

    char* ws = (char*)d_ws;
    uint32_t* xp   = (uint32_t*)ws;                         // 3,444,736 B
    char*     wq8s = (char*)(ws + 3444736);                 //   589,824 B
    float*    sAp  = (float*)(ws + 3444736 + 589824);       //     1,024 B

    // 1) pack x bits: 421 blocks (tail-guarded)
    pack_x_kernel<<<dim3((NPOS + 255) / 256), dim3(256), 0, stream>>>(x, xp);

    // 2) pack weights to +-1 i8, step-major + alpha
    pack_w8_kernel<<<dim3(OCH), dim3(256), 0, stream>>>(wt, wq8s, sAp);

    // 3) main: 32 images x 28 output-row-pairs
    xnor_mfma_kernel<<<dim3(896), dim3(512), 0, stream>>>(xp, wq8s, sAp, out);
}